// Round 3
// baseline (45.018 us; speedup 1.0000x reference)
//
#include <hip/hip_runtime.h>
#include <cstddef>

#define BB 2
#define TT 4
#define LL 384
#define CZ 128
#define NBINS 39
#define NBOUND 38

typedef float f32x4 __attribute__((ext_vector_type(4)));

// One block per (b, i). 512 threads.
// LDS: Wd 19.5K + Wj 10.5K + ps 8K + meta 6K = 44 KB -> 3 blocks/CU.
__global__ __launch_bounds__(512) void tpe_kernel(
    const int*   __restrict__ aatype,   // [B,T,L] int32
    const float* __restrict__ coords,   // [B,T,L,3] f32
    const int*   __restrict__ tmask,    // [B,T,L] bool->int32
    const int*   __restrict__ rmask,    // [B,L] bool->int32
    const float* __restrict__ weight,   // [82,128] f32
    const float* __restrict__ bias,     // [128] f32
    float*       __restrict__ out)      // [B,L,L,128] f32
{
    __shared__ float Wd_sh[NBINS * CZ];   // weight rows 0..38
    __shared__ float Wj_sh[21 * CZ];      // weight rows 61..81
    __shared__ float ps_sh[16 * CZ];      // subset sums of (W_m + W_i[aat_i_t] + bias)
    __shared__ int4  meta_sh[LL];         // {pk01, pk23, code|cnt<<8, scale_bits}

    const int bi  = blockIdx.x;
    const int b   = bi / LL;
    const int i   = bi - b * LL;
    const int tid = threadIdx.x;

    // ---- Phase 1a: issue staging loads into registers (writes deferred) ----
    // Combined range: [0,1248) -> Wd rows 0..38; [1248,1920) -> Wj rows 61..81.
    const float4* wsrc = (const float4*)weight;
    float4 st[4];
    #pragma unroll
    for (int k = 0; k < 4; ++k) {
        int idx = tid + k * 512;
        if (idx < 1920)
            st[k] = (idx < 1248) ? wsrc[idx] : wsrc[61 * (CZ / 4) + (idx - 1248)];
    }

    // ---- Phase 1b: ps[code][c] = sum over t in code of (W_m + W_i[aat_i_t] + bias) ----
    for (int idx = tid; idx < 16 * CZ; idx += 512) {
        int code = idx >> 7, c = idx & (CZ - 1);
        float v = 0.0f;
        if (code) {
            float base = weight[NBINS * CZ + c] + bias[c];   // W_m + bias
            v = (float)__popc(code) * base;
            #pragma unroll
            for (int t = 0; t < TT; ++t) {
                if (code & (1 << t)) {
                    int aa = aatype[(b * TT + t) * LL + i];
                    aa = min(max(aa, 0), 20);
                    v += weight[(NBINS + 1 + aa) * CZ + c];
                }
            }
        }
        ps_sh[idx] = v;
    }

    // ---- Phase 1c: one thread per j computes compacted meta (hides 1a latency) ----
    if (tid < LL) {
        #pragma clang fp contract(off)
        const int j  = tid;
        const int ri = rmask[b * LL + i];
        unsigned x = 0, y = 0;
        int code = 0, cnt = 0;
        #pragma unroll
        for (int t = 0; t < TT; ++t) {
            const int base = (b * TT + t) * LL;
            if (tmask[base + i] != 0 && tmask[base + j] != 0) {
                const float* ci = coords + (size_t)(base + i) * 3;
                const float* cj = coords + (size_t)(base + j) * 3;
                float dx = ci[0] - cj[0];
                float dy = ci[1] - cj[1];
                float dz = ci[2] - cj[2];
                float s  = dx * dx + dy * dy;    // numpy order: ((x+y)+z)
                s = s + dz * dz;
                float d = sqrtf(s);              // IEEE sqrt
                int bin = 0;
                #pragma unroll
                for (int k = 0; k < NBOUND; ++k) {
                    // folded at compile time; matches np.linspace(f64).astype(f32)
                    float bnd = (float)(3.25 + (double)k * (47.5 / 37.0));
                    bin += (d > bnd) ? 1 : 0;    // searchsorted side='left'
                }
                int aa = aatype[base + j];
                aa = min(max(aa, 0), 20);
                unsigned pk = (unsigned)(bin | (aa << 6));
                if (cnt < 2) x |= pk << (16 * cnt);
                else         y |= pk << (16 * (cnt - 2));
                code |= (1 << t);
                ++cnt;
            }
        }
        float scale = (ri != 0 && rmask[b * LL + j] != 0)
                      ? 1.0f / fmaxf((float)cnt, 1.0f) : 0.0f;
        int4 m;
        m.x = (int)x; m.y = (int)y; m.z = code | (cnt << 8);
        m.w = __float_as_int(scale);
        meta_sh[j] = m;
    }

    // ---- Phase 1a': commit staged weights to LDS ----
    {
        float4* wd = (float4*)Wd_sh;
        float4* wj = (float4*)Wj_sh;
        #pragma unroll
        for (int k = 0; k < 4; ++k) {
            int idx = tid + k * 512;
            if (idx < 1920) {
                if (idx < 1248) wd[idx] = st[k];
                else            wj[idx - 1248] = st[k];
            }
        }
    }
    __syncthreads();

    // ---- Phase 2: 32 lanes x f32x4 = 128 channels; 16 j-slots in flight ----
    const int cg = tid & 31;       // channel group (4 channels)
    const int jj = tid >> 5;       // 0..15
    const f32x4* Wd4 = (const f32x4*)Wd_sh;
    const f32x4* Wj4 = (const f32x4*)Wj_sh;
    const f32x4* ps4 = (const f32x4*)ps_sh;
    f32x4* outv = (f32x4*)(out + (size_t)(b * LL + i) * LL * CZ);

    #pragma unroll 4
    for (int j = jj; j < LL; j += 16) {
        int4 m = meta_sh[j];                          // broadcast b128
        f32x4 acc = ps4[(m.z & 15) * (CZ / 4) + cg];  // subset-sum init
        const int cnt = m.z >> 8;
        const unsigned x = (unsigned)m.x, y = (unsigned)m.y;
        for (int k = 0; k < cnt; ++k) {
            unsigned w2 = (k & 2) ? y : x;
            unsigned pk = (w2 >> ((k & 1) * 16)) & 0xFFFFu;
            f32x4 a  = Wd4[(pk & 63u) * (CZ / 4) + cg];
            f32x4 c2 = Wj4[(pk >> 6) * (CZ / 4) + cg];
            acc += a + c2;
        }
        const float s = __int_as_float(m.w);
        f32x4 o = acc * s;
        __builtin_nontemporal_store(o, &outv[j * (CZ / 4) + cg]);
    }
}

extern "C" void kernel_launch(void* const* d_in, const int* in_sizes, int n_in,
                              void* d_out, int out_size, void* d_ws, size_t ws_size,
                              hipStream_t stream) {
    const int*   aatype = (const int*)d_in[0];
    const float* coords = (const float*)d_in[1];
    const int*   tmask  = (const int*)d_in[2];
    const int*   rmask  = (const int*)d_in[3];
    const float* weight = (const float*)d_in[4];
    const float* bias   = (const float*)d_in[5];
    float* out = (float*)d_out;

    dim3 grid(BB * LL);
    dim3 block(512);
    tpe_kernel<<<grid, block, 0, stream>>>(aatype, coords, tmask, rmask, weight, bias, out);
}

// Round 4
// 32.612 us; speedup vs baseline: 1.3804x; 1.3804x over previous
//
#include <hip/hip_runtime.h>
#include <cstddef>
#include <type_traits>

#define BB 2
#define TT 4
#define LL 384
#define CZ 128
#define NBINS 39
#define NBOUND 38

typedef float f32x4 __attribute__((ext_vector_type(4)));

// One block per (b, i). 512 threads.
// LDS: Wd' 19.5K + Wj 10.5K + pre 2K + meta 6K = 38 KB -> 4 blocks/CU cap.
__global__ __launch_bounds__(512) void tpe_kernel(
    const int*   __restrict__ aatype,   // [B,T,L] int32
    const float* __restrict__ coords,   // [B,T,L,3] f32
    const int*   __restrict__ tmask,    // [B,T,L] bool->int32
    const int*   __restrict__ rmask,    // [B,L] bool->int32
    const float* __restrict__ weight,   // [82,128] f32
    const float* __restrict__ bias,     // [128] f32
    float*       __restrict__ out)      // [B,L,L,128] f32
{
    __shared__ float Wd_sh[NBINS * CZ];  // rows 0..38, pre-folded with (W_m + bias)
    __shared__ float Wj_sh[21 * CZ];     // rows 61..81
    __shared__ float pre_sh[TT * CZ];    // W_i[aat_i_t]
    __shared__ int4  meta_sh[LL];        // {pk01, pk23, 0, scale_bits}; pk: bin|aa<<6|act<<11

    const int bi  = blockIdx.x;
    const int b   = bi / LL;
    const int i   = bi - b * LL;
    const int tid = threadIdx.x;
    const int bT  = b * TT;

    // Block-uniform i-activity code (compiler sees blockIdx-only addressing).
    int icode = 0;
    #pragma unroll
    for (int t = 0; t < TT; ++t)
        icode |= (tmask[(bT + t) * LL + i] != 0) << t;

    // ---- Phase 1a: stage Wd (+Wm+bias folded) and Wj into LDS ----
    {
        const float4* wsrc = (const float4*)weight;
        const float4* bs4  = (const float4*)bias;
        float4* wd = (float4*)Wd_sh;
        float4* wj = (float4*)Wj_sh;
        #pragma unroll
        for (int k = 0; k < 4; ++k) {
            int idx = tid + k * 512;
            if (idx < 1248) {
                float4 w  = wsrc[idx];
                float4 wm = wsrc[NBINS * (CZ / 4) + (idx & 31)];
                float4 b4 = bs4[idx & 31];
                w.x += wm.x + b4.x; w.y += wm.y + b4.y;
                w.z += wm.z + b4.z; w.w += wm.w + b4.w;
                wd[idx] = w;
            } else if (idx < 1920) {
                wj[idx - 1248] = wsrc[61 * (CZ / 4) + (idx - 1248)];
            }
        }
    }

    // ---- Phase 1b: pre[t][c] = W_i[aat_i_t][c] (1 round) ----
    {
        int t = tid >> 7, c = tid & (CZ - 1);
        int aa = aatype[(bT + t) * LL + i];
        aa = min(max(aa, 0), 20);
        pre_sh[tid] = weight[(NBINS + 1 + aa) * CZ + c];
    }

    // ---- Phase 1c: per-j meta (one thread per j) ----
    if (tid < LL) {
        #pragma clang fp contract(off)
        const int j  = tid;
        const int ri = rmask[b * LL + i];
        unsigned pks[TT] = {0, 0, 0, 0};
        int cnt = 0;
        #pragma unroll
        for (int t = 0; t < TT; ++t) {
            if (icode & (1 << t)) {                 // wave-uniform branch
                const int base = (bT + t) * LL;
                if (tmask[base + j] != 0) {
                    const float* ci = coords + (size_t)(base + i) * 3;
                    const float* cj = coords + (size_t)(base + j) * 3;
                    float dx = ci[0] - cj[0];
                    float dy = ci[1] - cj[1];
                    float dz = ci[2] - cj[2];
                    float s  = dx * dx + dy * dy;   // numpy order ((x+y)+z)
                    s = s + dz * dz;
                    float d = sqrtf(s);             // IEEE sqrt
                    int bin = 0;
                    #pragma unroll
                    for (int k = 0; k < NBOUND; ++k) {
                        float bnd = (float)(3.25 + (double)k * (47.5 / 37.0));
                        bin += (d > bnd) ? 1 : 0;   // searchsorted side='left'
                    }
                    int aa = aatype[base + j];
                    aa = min(max(aa, 0), 20);
                    pks[t] = (unsigned)(bin | (aa << 6) | (1 << 11));
                    ++cnt;
                }
            }
        }
        float scale = (ri != 0 && rmask[b * LL + j] != 0)
                      ? 1.0f / fmaxf((float)cnt, 1.0f) : 0.0f;
        int4 m;
        m.x = (int)(pks[0] | (pks[1] << 16));
        m.y = (int)(pks[2] | (pks[3] << 16));
        m.z = 0;
        m.w = __float_as_int(scale);
        meta_sh[j] = m;
    }
    __syncthreads();

    // ---- Phase 2: statically specialized on icode; no divergent branches ----
    const int cg = tid & 31;       // channel group (4 channels)
    const int jj = tid >> 5;       // 0..15
    const f32x4* Wd4  = (const f32x4*)Wd_sh;
    const f32x4* Wj4  = (const f32x4*)Wj_sh;
    const f32x4* pre4 = (const f32x4*)pre_sh;
    f32x4* outv = (f32x4*)(out + (size_t)(b * LL + i) * LL * CZ);

    auto run = [&](auto cmc) {
        constexpr int CM = decltype(cmc)::value;
        f32x4 pr[TT];
        #pragma unroll
        for (int t = 0; t < TT; ++t)
            if (CM & (1 << t)) pr[t] = pre4[t * (CZ / 4) + cg];
        #pragma unroll 4
        for (int j = jj; j < LL; j += 16) {
            int4 m = meta_sh[j];                    // broadcast b128
            f32x4 acc = {0.f, 0.f, 0.f, 0.f};
            #pragma unroll
            for (int t = 0; t < TT; ++t) {
                if (CM & (1 << t)) {
                    unsigned h = (unsigned)(t < 2 ? m.x : m.y);
                    unsigned pk = (h >> ((t & 1) * 16)) & 0xFFFFu;
                    f32x4 a = Wd4[(pk & 63u) * (CZ / 4) + cg];
                    f32x4 c = Wj4[((pk >> 6) & 31u) * (CZ / 4) + cg];
                    float mt = (float)((pk >> 11) & 1u);
                    acc += (a + c + pr[t]) * mt;
                }
            }
            float s = __int_as_float(m.w);
            outv[j * (CZ / 4) + cg] = acc * s;
        }
    };

    #define RUN_CASE(K) case K: run(std::integral_constant<int, K>{}); break;
    switch (icode) {
        RUN_CASE(0)  RUN_CASE(1)  RUN_CASE(2)  RUN_CASE(3)
        RUN_CASE(4)  RUN_CASE(5)  RUN_CASE(6)  RUN_CASE(7)
        RUN_CASE(8)  RUN_CASE(9)  RUN_CASE(10) RUN_CASE(11)
        RUN_CASE(12) RUN_CASE(13) RUN_CASE(14) RUN_CASE(15)
    }
    #undef RUN_CASE
}

extern "C" void kernel_launch(void* const* d_in, const int* in_sizes, int n_in,
                              void* d_out, int out_size, void* d_ws, size_t ws_size,
                              hipStream_t stream) {
    const int*   aatype = (const int*)d_in[0];
    const float* coords = (const float*)d_in[1];
    const int*   tmask  = (const int*)d_in[2];
    const int*   rmask  = (const int*)d_in[3];
    const float* weight = (const float*)d_in[4];
    const float* bias   = (const float*)d_in[5];
    float* out = (float*)d_out;

    dim3 grid(BB * LL);
    dim3 block(512);
    tpe_kernel<<<grid, block, 0, stream>>>(aatype, coords, tmask, rmask, weight, bias, out);
}